// Round 1
// baseline (9482.727 us; speedup 1.0000x reference)
//
#include <hip/hip_runtime.h>
#include <hip/hip_bf16.h>
#include <cstdint>

// ---------------------------------------------------------------------------
// BiLSTM: x[2048,1024] -> bidirectional LSTM (H=1024) -> FC to 1000 classes.
//   1. convert_all: fp32 -> f16 copies of x, W_ih_f, W_ih_b, fc_W
//   2. gemm_f16<0>: x_proj_d = x_d @ W_ih_d^T + b_ih + b_hh   (f16 MFMA)
//   3. lstm_rec R6: XCD-localized recurrence. 512 blocks launched; blocks
//      with blk%8==0 (-> XCD0 under round-robin dispatch) run the fwd
//      chain, blk%8==1 (-> XCD1) run bwd, rest exit. h broadcast goes
//      through the XCD-shared L2: producers plain-store (write-through L1)
//      into hc_fast, consumers poll with sc0 (L1-bypass) dwordx4 loads.
//      Agent-scope mirror buffer + every-16th-retry fallback keeps it
//      correct if the placement heuristic is wrong. Epoch-salted tags
//      ((epoch<<12)+t) make cross-run stale L2 lines unmatchable.
//      Tail: butterfly reduce -> cndmask+4x ds_bpermute redistribution
//      (replaces LDS transpose), publish split across lanes 0/2.
//   4. gemm_f16<1>: out = h_hist @ fc_W^T + fc_b
// ---------------------------------------------------------------------------

typedef __fp16 h2 __attribute__((ext_vector_type(2)));
typedef __fp16 h8 __attribute__((ext_vector_type(8)));
typedef float f4 __attribute__((ext_vector_type(4)));
typedef unsigned int u32x4 __attribute__((ext_vector_type(4)));
typedef unsigned long long u64;

#define T_LEN 2048

static __device__ __forceinline__ unsigned int packh2(float a, float b) {
  h2 r = __builtin_amdgcn_cvt_pkrtz(a, b);
  return __builtin_bit_cast(unsigned int, r);
}
static __device__ __forceinline__ float fdot2u(unsigned int a, unsigned int b, float c) {
  return __builtin_amdgcn_fdot2(__builtin_bit_cast(h2, a), __builtin_bit_cast(h2, b), c, false);
}
static __device__ __forceinline__ float sigmoidf_(float x) {
  return 1.f / (1.f + __expf(-x));
}
static __device__ __forceinline__ float tanhf_(float x) {
  float e = __expf(-2.f * fabsf(x));
  float r = (1.f - e) / (1.f + e);
  return copysignf(r, x);
}

// fast-path ops: L1-bypass load served by the XCD-local L2; plain store
// (CDNA vector L1 is write-through, so the store lands in the shared L2).
static __device__ __forceinline__ void load4_sc0(const u64* p, u32x4& v) {
  asm volatile(
      "global_load_dwordx4 %0, %1, off sc0\n\t"
      "s_waitcnt vmcnt(0)"
      : "=&v"(v)
      : "v"(p)
      : "memory");
}
static __device__ __forceinline__ void store_u64_plain(u64* p, u64 v) {
  asm volatile("global_store_dwordx2 %0, %1, off" :: "v"(p), "v"(v) : "memory");
}

// ---------------------------------------------------------------------------
__global__ void convert_all(const float* __restrict__ x, const float* __restrict__ wf,
                            const float* __restrict__ wb, const float* __restrict__ fcw,
                            _Float16* __restrict__ xf, _Float16* __restrict__ wff,
                            _Float16* __restrict__ wbf, _Float16* __restrict__ fcwf) {
  const size_t SX = 2097152, SW = 4194304, SFC = 2097152;
  size_t i = (size_t)blockIdx.x * 256 + threadIdx.x;
  if (i < SX) {
    xf[i] = (_Float16)x[i];
  } else if (i < SX + SW) {
    size_t j = i - SX; wff[j] = (_Float16)wf[j];
  } else if (i < SX + 2 * SW) {
    size_t j = i - SX - SW; wbf[j] = (_Float16)wb[j];
  } else if (i < SX + 2 * SW + SFC) {
    size_t j = i - SX - 2 * SW;
    int row = (int)(j >> 11), col = (int)(j & 2047);
    fcwf[j] = (row < 1000) ? (_Float16)fcw[(size_t)row * 2048 + col] : (_Float16)0.f;
  }
}

// epoch bump + seed gen-0 tags (payload h=0, tag=epoch<<12) in both buffers.
// Agent-scope stores reach the IC, so any XCD's first L2 miss fetches them.
__global__ void init_state(u64* __restrict__ hc, u64* __restrict__ hcf,
                           unsigned* __restrict__ ep) {
  __shared__ unsigned sbs;
  if (threadIdx.x == 0) sbs = atomicAdd(ep, 1u) << 12;
  __syncthreads();
  u64 v = (u64)sbs;
  for (int i = threadIdx.x; i < 2048; i += 256) {
    __hip_atomic_store(&hc[i], v, __ATOMIC_RELAXED, __HIP_MEMORY_SCOPE_AGENT);
    __hip_atomic_store(&hcf[i], v, __ATOMIC_RELAXED, __HIP_MEMORY_SCOPE_AGENT);
  }
}

// ---------------------------------------------------------------------------
// f16 GEMM, 128x128 tile, BK=64 (unchanged — verified R2/R3/R4)
// ---------------------------------------------------------------------------
#define LSTR 80

template <int MODE>
__global__ __launch_bounds__(256, 2) void gemm_f16(
    const _Float16* __restrict__ A, const _Float16* __restrict__ B,
    const float* __restrict__ bias1, const float* __restrict__ bias2,
    void* __restrict__ Cout, int M, int N, int K, int nout, int rev) {
  __shared__ _Float16 As[128 * LSTR];
  __shared__ _Float16 Bs[128 * LSTR];

  const int tid = threadIdx.x;
  const int ntn = N >> 7;
  const int tm = blockIdx.x / ntn, tn = blockIdx.x % ntn;
  const int wid = tid >> 6, lane = tid & 63;
  const int wr = wid >> 1, wc = wid & 1;
  const int quad = lane >> 4, l16 = lane & 15;

  const int srow = tid >> 1, seg = tid & 1;
  const int arow = rev ? (M - 1 - (tm * 128 + srow)) : (tm * 128 + srow);
  const int brow = tn * 128 + srow;

  f4 acc[4][4];
#pragma unroll
  for (int i = 0; i < 4; ++i)
#pragma unroll
    for (int j = 0; j < 4; ++j) acc[i][j] = (f4)0.f;

  for (int k0 = 0; k0 < K; k0 += 64) {
    uint4 va[4], vb[4];
    const uint4* gpa = (const uint4*)(A + (size_t)arow * K + k0 + seg * 32);
    const uint4* gpb = (const uint4*)(B + (size_t)brow * K + k0 + seg * 32);
#pragma unroll
    for (int c = 0; c < 4; ++c) va[c] = gpa[c];
#pragma unroll
    for (int c = 0; c < 4; ++c) vb[c] = gpb[c];

    __syncthreads();
    uint4* lpa = (uint4*)&As[srow * LSTR + seg * 32];
    uint4* lpb = (uint4*)&Bs[srow * LSTR + seg * 32];
#pragma unroll
    for (int c = 0; c < 4; ++c) lpa[c] = va[c];
#pragma unroll
    for (int c = 0; c < 4; ++c) lpb[c] = vb[c];
    __syncthreads();

#pragma unroll
    for (int kk = 0; kk < 64; kk += 32) {
      h8 af[4], bf[4];
#pragma unroll
      for (int i = 0; i < 4; ++i) {
        int m = wr * 64 + i * 16 + l16;
        af[i] = *(const h8*)&As[m * LSTR + kk + quad * 8];
        int n = wc * 64 + i * 16 + l16;
        bf[i] = *(const h8*)&Bs[n * LSTR + kk + quad * 8];
      }
#pragma unroll
      for (int i = 0; i < 4; ++i)
#pragma unroll
        for (int j = 0; j < 4; ++j)
          acc[i][j] = __builtin_amdgcn_mfma_f32_16x16x32_f16(af[i], bf[j], acc[i][j], 0, 0, 0);
    }
  }

  const int cm0 = tm * 128 + wr * 64, cn0 = tn * 128 + wc * 64;
#pragma unroll
  for (int i = 0; i < 4; ++i) {
#pragma unroll
    for (int j = 0; j < 4; ++j) {
      int n = cn0 + j * 16 + l16;
#pragma unroll
      for (int r = 0; r < 4; ++r) {
        int m = cm0 + i * 16 + quad * 4 + r;
        float v = acc[i][j][r];
        if (MODE == 0) {
          v += bias1[n] + bias2[n];
          ((_Float16*)Cout)[(size_t)m * N + n] = (_Float16)v;
        } else {
          if (n < nout) ((float*)Cout)[(size_t)m * nout + n] = v + bias1[n];
        }
      }
    }
  }
}

// ---------------------------------------------------------------------------
// Persistent BiLSTM recurrence, R6 (XCD-localized).
// 512 blocks launched; workers: blk%8==0 -> fwd on XCD0, blk%8==1 -> bwd on
// XCD1 (round-robin dispatch), others exit. 64 worker blocks/XCD = 2/CU
// (VGPR<=128 guarantees co-residency). Block owns 16 h (j0..j0+15) = 64 W_hh
// rows; wave wv owns jj {4wv..4wv+3}; lane = [gate(2b)|kq(4b)].
// hc_fast: [buf][dir][512] u64, word w = [h2(h[2w],h[2w+1]) | tag32],
// tag = (epoch<<12) + gen. Producer lanes 0/2 plain-store (-> local L2);
// consumers poll their 16B with sc0 dwordx4; agent-scope mirror hc polled
// every 16th retry as placement-independent fallback. 2-buffer protocol and
// single barrier/step unchanged from R5.
// ---------------------------------------------------------------------------
__global__ __launch_bounds__(256, 2) void lstm_rec(
    const float* __restrict__ Whh_f, const float* __restrict__ Whh_b,
    const _Float16* __restrict__ xp,   // [2][2048][4096]
    u64* __restrict__ hc,              // slow agent-scope mirror [2][2][512]
    u64* __restrict__ hcf,             // fast XCD-L2 buffer     [2][2][512]
    unsigned* __restrict__ ep,         // epoch counter (post-incremented)
    _Float16* __restrict__ hhist) {    // [2048][2048]
  const int tid = threadIdx.x;
  const int blk = blockIdx.x;
  const int dir = blk & 7;   // == XCD id under round-robin dispatch
  if (dir > 1) return;       // workers only on XCD0 (fwd) / XCD1 (bwd)
  const int ib = blk >> 3;   // 0..63
  const int j0 = ib * 16;
  const int wv = tid >> 6;
  const int l = tid & 63;
  const int g = l >> 4;      // gate 0..3 (i,f,g,o)
  const int kq = l & 15;     // 16 k-slices of 64
  const int q = l & 3;       // cell-replica jj index
  const int wrow0 = g * 1024 + j0 + 4 * wv;

  const unsigned SB =
      (__hip_atomic_load(ep, __ATOMIC_RELAXED, __HIP_MEMORY_SCOPE_AGENT) - 1u) << 12;

  const float* Whh = dir ? Whh_b : Whh_f;
  const _Float16* xpd = xp + (size_t)dir * (2048u * 4096u);

  __shared__ unsigned int lds_h[2][16 * 36];  // [buf][seg stride 36]

  // one-time: W_hh[wrow0+j][kq*64 .. +63] -> f16 regs (4 rows x 32 dwords)
  unsigned int w[4][32];
#pragma unroll
  for (int j = 0; j < 4; ++j) {
    const float* wp = Whh + (size_t)(wrow0 + j) * 1024 + kq * 64;
#pragma unroll
    for (int i = 0; i < 16; ++i) {
      float4 v = ((const float4*)wp)[i];
      w[j][2 * i] = packh2(v.x, v.y);
      w[j][2 * i + 1] = packh2(v.z, v.w);
    }
  }

  float c = 0.f;  // cell state for jj=4wv+q (replicated across 16 lanes)

  // x_proj for t=0 (4 consecutive f16 at wrow0)
  uint2 xv = *(const uint2*)(xpd + wrow0);
  h2 x01 = __builtin_bit_cast(h2, xv.x);
  h2 x23 = __builtin_bit_cast(h2, xv.y);
  float xf[4] = {(float)x01[0], (float)x01[1], (float)x23[0], (float)x23[1]};

  for (int t = 0; t < T_LEN; ++t) {
    const int buf = t & 1;
    const unsigned exp0 = SB + (unsigned)t;
    // ---- poll own 16B (words 2tid, 2tid+1): fast L2 path + slow fallback ----
    unsigned d0 = 0, d1 = 0;
    {
      const size_t boff = ((size_t)buf * 2 + dir) * 512 + 2 * tid;
      const u64* f = hcf + boff;
      u64* s = hc + boff;
      int cnt = 0;
      for (;;) {
        u32x4 fv;
        load4_sc0(f, fv);  // {tag0, pay0, tag1, pay1}
        if (fv[0] == exp0 && fv[2] == exp0) { d0 = fv[1]; d1 = fv[3]; break; }
        if ((++cnt & 15) == 0) {
          u64 sa = __hip_atomic_load(&s[0], __ATOMIC_RELAXED, __HIP_MEMORY_SCOPE_AGENT);
          u64 sb = __hip_atomic_load(&s[1], __ATOMIC_RELAXED, __HIP_MEMORY_SCOPE_AGENT);
          if ((unsigned)sa == exp0 && (unsigned)sb == exp0) {
            d0 = (unsigned)(sa >> 32);
            d1 = (unsigned)(sb >> 32);
            break;
          }
          if (cnt > (1 << 12)) break;  // bailout: fail absmax, never hang
        }
      }
    }

    // prefetch NEXT step's x_proj (after poll loads -> off the vmcnt path)
    int tnx = (t + 1 < T_LEN) ? t + 1 : t;
    uint2 xn = *(const uint2*)(xpd + (size_t)tnx * 4096 + wrow0);

    // stage h payload: dwords 2tid,2tid+1 -> seg tid>>4, offset 2*(tid&15)
    *(uint2*)&lds_h[buf][(tid >> 4) * 36 + 2 * (tid & 15)] = make_uint2(d0, d1);
    __syncthreads();  // single barrier per step

    // ---- dot: 4 rows x 64-elem slice; 8 ds_read_b128, 128 fdot2 ----
    float acc0 = 0.f, acc1 = 0.f, acc2 = 0.f, acc3 = 0.f;
    const uint4* hp = (const uint4*)&lds_h[buf][kq * 36];
#pragma unroll
    for (int i = 0; i < 8; ++i) {
      uint4 hv = hp[i];
      acc0 = fdot2u(w[0][4 * i + 0], hv.x, acc0);
      acc0 = fdot2u(w[0][4 * i + 1], hv.y, acc0);
      acc0 = fdot2u(w[0][4 * i + 2], hv.z, acc0);
      acc0 = fdot2u(w[0][4 * i + 3], hv.w, acc0);
      acc1 = fdot2u(w[1][4 * i + 0], hv.x, acc1);
      acc1 = fdot2u(w[1][4 * i + 1], hv.y, acc1);
      acc1 = fdot2u(w[1][4 * i + 2], hv.z, acc1);
      acc1 = fdot2u(w[1][4 * i + 3], hv.w, acc1);
      acc2 = fdot2u(w[2][4 * i + 0], hv.x, acc2);
      acc2 = fdot2u(w[2][4 * i + 1], hv.y, acc2);
      acc2 = fdot2u(w[2][4 * i + 2], hv.z, acc2);
      acc2 = fdot2u(w[2][4 * i + 3], hv.w, acc2);
      acc3 = fdot2u(w[3][4 * i + 0], hv.x, acc3);
      acc3 = fdot2u(w[3][4 * i + 1], hv.y, acc3);
      acc3 = fdot2u(w[3][4 * i + 2], hv.z, acc3);
      acc3 = fdot2u(w[3][4 * i + 3], hv.w, acc3);
    }
    // butterfly reduce over kq (lane bits 0..3); all lanes get group sums
#pragma unroll
    for (int m = 1; m < 16; m <<= 1) {
      acc0 += __shfl_xor(acc0, m, 64);
      acc1 += __shfl_xor(acc1, m, 64);
      acc2 += __shfl_xor(acc2, m, 64);
      acc3 += __shfl_xor(acc3, m, 64);
    }

    // redistribute preacts: every lane holds full sums for its gate g, rows
    // 4wv+0..3. Lane picks its q's accumulator (+x_proj), then reads the
    // 4 gates' values for row q from lanes {q, 16+q, 32+q, 48+q}.
    float av = (q == 0) ? (acc0 + xf[0]) : (q == 1) ? (acc1 + xf[1])
             : (q == 2) ? (acc2 + xf[2]) : (acc3 + xf[3]);
    float pi = __shfl(av, q, 64);
    float pf = __shfl(av, 16 + q, 64);
    float pg = __shfl(av, 32 + q, 64);
    float po = __shfl(av, 48 + q, 64);

    float ii = sigmoidf_(pi);
    float ff = sigmoidf_(pf);
    float g_ = tanhf_(pg);
    float oo = sigmoidf_(po);
    c = ff * c + ii * g_;
    float h = oo * tanhf_(c);  // h for jj=4wv+q

    // publish: lanes 0 and 2 each pack (own h, neighbor h) and store one u64
    float hx = __shfl_xor(h, 1, 64);
    if (l < 4 && (l & 1) == 0) {
      unsigned pk = packh2(h, hx);  // lane0:(h0,h1)  lane2:(h2,h3)
      u64 wv64 = ((u64)pk << 32) | (u64)(SB + (unsigned)(t + 1));
      size_t widx = ((size_t)((t + 1) & 1) * 2 + dir) * 512 +
                    (size_t)(ib * 8 + 2 * wv + (l >> 1));
      store_u64_plain(hcf + widx, wv64);  // fast: local-XCD L2 (write-through L1)
      __hip_atomic_store(&hc[widx], wv64, __ATOMIC_RELAXED, __HIP_MEMORY_SCOPE_AGENT);
      // hhist AFTER publish: off the critical sync path
      int tout = dir ? (T_LEN - 1 - t) : t;
      *(unsigned*)&hhist[(size_t)tout * 2048 +
                         (size_t)(dir * 1024 + j0 + 4 * wv + (l >> 1) * 2)] = pk;
    }

    // convert next-step xp (prefetched above)
    x01 = __builtin_bit_cast(h2, xn.x);
    x23 = __builtin_bit_cast(h2, xn.y);
    xf[0] = (float)x01[0]; xf[1] = (float)x01[1];
    xf[2] = (float)x23[0]; xf[3] = (float)x23[1];
  }
}

// ---------------------------------------------------------------------------
extern "C" void kernel_launch(void* const* d_in, const int* in_sizes, int n_in,
                              void* d_out, int out_size, void* d_ws, size_t ws_size,
                              hipStream_t stream) {
  (void)in_sizes; (void)n_in; (void)out_size; (void)ws_size;
  const float* x     = (const float*)d_in[0];
  const float* Wih_f = (const float*)d_in[1];
  const float* Whh_f = (const float*)d_in[2];
  const float* bih_f = (const float*)d_in[3];
  const float* bhh_f = (const float*)d_in[4];
  const float* Wih_b = (const float*)d_in[5];
  const float* Whh_b = (const float*)d_in[6];
  const float* bih_b = (const float*)d_in[7];
  const float* bhh_b = (const float*)d_in[8];
  const float* fcW   = (const float*)d_in[9];
  const float* fcb   = (const float*)d_in[10];

  char* ws = (char*)d_ws;
  _Float16* xf16   = (_Float16*)(ws + 0);
  _Float16* wih16f = (_Float16*)(ws + 4194304);
  _Float16* wih16b = (_Float16*)(ws + 12582912);
  _Float16* fcw16  = (_Float16*)(ws + 20971520);
  _Float16* xp16   = (_Float16*)(ws + 25165824);   // [2][2048][4096]
  _Float16* hhist  = (_Float16*)(ws + 58720256);   // [2048][2048]
  u64*      hc     = (u64*)     (ws + 67108864);   // slow mirror [2][2][512]
  u64*      hcf    = (u64*)     (ws + 67125248);   // fast buffer [2][2][512]
  unsigned* epoch  = (unsigned*)(ws + 67141632);   // epoch counter

  const size_t SX = 2097152, SW = 4194304, SFC = 2097152;
  const size_t total_cvt = SX + 2 * SW + SFC;

  convert_all<<<dim3((unsigned)((total_cvt + 255) / 256)), 256, 0, stream>>>(
      x, Wih_f, Wih_b, fcW, xf16, wih16f, wih16b, fcw16);
  init_state<<<1, 256, 0, stream>>>(hc, hcf, epoch);

  gemm_f16<0><<<dim3(512), 256, 0, stream>>>(xf16, wih16f, bih_f, bhh_f,
                                             (void*)xp16, 2048, 4096, 1024, 4096, 0);
  gemm_f16<0><<<dim3(512), 256, 0, stream>>>(xf16, wih16b, bih_b, bhh_b,
                                             (void*)(xp16 + (size_t)2048 * 4096),
                                             2048, 4096, 1024, 4096, 1);

  lstm_rec<<<dim3(512), 256, 0, stream>>>(Whh_f, Whh_b, xp16, hc, hcf, epoch, hhist);

  gemm_f16<1><<<dim3(128), 256, 0, stream>>>(hhist, fcw16, fcb, nullptr,
                                             d_out, 2048, 1024, 2048, 1000, 0);
}

// Round 2
// 5124.720 us; speedup vs baseline: 1.8504x; 1.8504x over previous
//
#include <hip/hip_runtime.h>
#include <hip/hip_bf16.h>
#include <cstdint>

// ---------------------------------------------------------------------------
// BiLSTM: x[2048,1024] -> bidirectional LSTM (H=1024) -> FC to 1000 classes.
//   1. convert_all: fp32 -> f16 copies of x, W_ih_f, W_ih_b, fc_W
//   2. gemm_f16<0>: x_proj_d = x_d @ W_ih_d^T + b_ih + b_hh   (f16 MFMA)
//   3. lstm_rec R7: XCD-localized recurrence with HW-verified placement.
//      512 blocks; each reads HW_REG_XCC_ID. XCD0 blocks claim the 64 fwd
//      slots, XCD1 the 64 bwd slots (device atomics); a deficit backstop
//      (after arrival counting) fills missing slots from any XCD ->
//      deadlock-free. Handshake: producers plain-store 16B (write-through
//      L1 -> local XCD L2) into hcf; consumers poll with one sc0 dwordx4;
//      agent-scope mirror checked EVERY 4th iteration (R6's 16x cadence was
//      the regression) -> downside bounded at ~R5 latency. Epoch-salted
//      tags kill cross-replay staleness. Lane layout: lane = [rr(2b)|kq(4b)],
//      4 accs = 4 GATES of unit 4wv+rr; kq-reduce via 4 DPP v_add rounds
//      (VALU, no LDS pipe); no redistribution needed; publish = 2 shfl +
//      one dwordx4.
//   4. gemm_f16<1>: out = h_hist @ fc_W^T + fc_b
// ---------------------------------------------------------------------------

typedef __fp16 h2 __attribute__((ext_vector_type(2)));
typedef __fp16 h8 __attribute__((ext_vector_type(8)));
typedef float f4 __attribute__((ext_vector_type(4)));
typedef unsigned int u32x4 __attribute__((ext_vector_type(4)));
typedef unsigned long long u64;

#define T_LEN 2048

static __device__ __forceinline__ unsigned int packh2(float a, float b) {
  h2 r = __builtin_amdgcn_cvt_pkrtz(a, b);
  return __builtin_bit_cast(unsigned int, r);
}
static __device__ __forceinline__ float fdot2u(unsigned int a, unsigned int b, float c) {
  return __builtin_amdgcn_fdot2(__builtin_bit_cast(h2, a), __builtin_bit_cast(h2, b), c, false);
}
static __device__ __forceinline__ float sigmoidf_(float x) {
  return 1.f / (1.f + __expf(-x));
}
static __device__ __forceinline__ float tanhf_(float x) {
  float e = __expf(-2.f * fabsf(x));
  float r = (1.f - e) / (1.f + e);
  return copysignf(r, x);
}
static __device__ __forceinline__ int xcc_id() {
  int v;
  asm("s_getreg_b32 %0, hwreg(HW_REG_XCC_ID, 0, 4)" : "=s"(v));
  return v & 7;
}
// fast-path poll: L1-bypass 16B load served by the (XCD-local) L2
static __device__ __forceinline__ void load4_sc0(const u64* p, u32x4& v) {
  asm volatile(
      "global_load_dwordx4 %0, %1, off sc0\n\t"
      "s_waitcnt vmcnt(0)"
      : "=&v"(v)
      : "v"(p)
      : "memory");
}

// 16-lane (DPP-row) sum reduction: xor1, xor2 (quad_perm), then
// row_half_mirror (8-group), row_mirror (16-group). All lanes get row sum.
#define DPP_ADD1(v, CTRL)                                                      \
  v += __builtin_bit_cast(                                                     \
      float, __builtin_amdgcn_update_dpp(0, __builtin_bit_cast(int, v), CTRL,  \
                                         0xf, 0xf, true))
#define DPP_ROUND(CTRL)                                                        \
  DPP_ADD1(acc0, CTRL);                                                        \
  DPP_ADD1(acc1, CTRL);                                                        \
  DPP_ADD1(acc2, CTRL);                                                        \
  DPP_ADD1(acc3, CTRL)

// ---------------------------------------------------------------------------
__global__ void convert_all(const float* __restrict__ x, const float* __restrict__ wf,
                            const float* __restrict__ wb, const float* __restrict__ fcw,
                            _Float16* __restrict__ xf, _Float16* __restrict__ wff,
                            _Float16* __restrict__ wbf, _Float16* __restrict__ fcwf) {
  const size_t SX = 2097152, SW = 4194304, SFC = 2097152;
  size_t i = (size_t)blockIdx.x * 256 + threadIdx.x;
  if (i < SX) {
    xf[i] = (_Float16)x[i];
  } else if (i < SX + SW) {
    size_t j = i - SX; wff[j] = (_Float16)wf[j];
  } else if (i < SX + 2 * SW) {
    size_t j = i - SX - SW; wbf[j] = (_Float16)wb[j];
  } else if (i < SX + 2 * SW + SFC) {
    size_t j = i - SX - 2 * SW;
    int row = (int)(j >> 11), col = (int)(j & 2047);
    fcwf[j] = (row < 1000) ? (_Float16)fcw[(size_t)row * 2048 + col] : (_Float16)0.f;
  }
}

// epoch bump + zero claim counters + seed gen-0 tags in both buffers.
__global__ void init_state(u64* __restrict__ hc, u64* __restrict__ hcf,
                           unsigned* __restrict__ ep, int* __restrict__ cl) {
  __shared__ unsigned sbs;
  if (threadIdx.x == 0) sbs = atomicAdd(ep, 1u) << 12;
  if (threadIdx.x < 8) cl[threadIdx.x] = 0;
  __syncthreads();
  u64 v = (u64)sbs;
  for (int i = threadIdx.x; i < 2048; i += 256) {
    __hip_atomic_store(&hc[i], v, __ATOMIC_RELAXED, __HIP_MEMORY_SCOPE_AGENT);
    __hip_atomic_store(&hcf[i], v, __ATOMIC_RELAXED, __HIP_MEMORY_SCOPE_AGENT);
  }
}

// ---------------------------------------------------------------------------
// f16 GEMM, 128x128 tile, BK=64 (unchanged — verified R2/R3/R4)
// ---------------------------------------------------------------------------
#define LSTR 80

template <int MODE>
__global__ __launch_bounds__(256, 2) void gemm_f16(
    const _Float16* __restrict__ A, const _Float16* __restrict__ B,
    const float* __restrict__ bias1, const float* __restrict__ bias2,
    void* __restrict__ Cout, int M, int N, int K, int nout, int rev) {
  __shared__ _Float16 As[128 * LSTR];
  __shared__ _Float16 Bs[128 * LSTR];

  const int tid = threadIdx.x;
  const int ntn = N >> 7;
  const int tm = blockIdx.x / ntn, tn = blockIdx.x % ntn;
  const int wid = tid >> 6, lane = tid & 63;
  const int wr = wid >> 1, wc = wid & 1;
  const int quad = lane >> 4, l16 = lane & 15;

  const int srow = tid >> 1, seg = tid & 1;
  const int arow = rev ? (M - 1 - (tm * 128 + srow)) : (tm * 128 + srow);
  const int brow = tn * 128 + srow;

  f4 acc[4][4];
#pragma unroll
  for (int i = 0; i < 4; ++i)
#pragma unroll
    for (int j = 0; j < 4; ++j) acc[i][j] = (f4)0.f;

  for (int k0 = 0; k0 < K; k0 += 64) {
    uint4 va[4], vb[4];
    const uint4* gpa = (const uint4*)(A + (size_t)arow * K + k0 + seg * 32);
    const uint4* gpb = (const uint4*)(B + (size_t)brow * K + k0 + seg * 32);
#pragma unroll
    for (int c = 0; c < 4; ++c) va[c] = gpa[c];
#pragma unroll
    for (int c = 0; c < 4; ++c) vb[c] = gpb[c];

    __syncthreads();
    uint4* lpa = (uint4*)&As[srow * LSTR + seg * 32];
    uint4* lpb = (uint4*)&Bs[srow * LSTR + seg * 32];
#pragma unroll
    for (int c = 0; c < 4; ++c) lpa[c] = va[c];
#pragma unroll
    for (int c = 0; c < 4; ++c) lpb[c] = vb[c];
    __syncthreads();

#pragma unroll
    for (int kk = 0; kk < 64; kk += 32) {
      h8 af[4], bf[4];
#pragma unroll
      for (int i = 0; i < 4; ++i) {
        int m = wr * 64 + i * 16 + l16;
        af[i] = *(const h8*)&As[m * LSTR + kk + quad * 8];
        int n = wc * 64 + i * 16 + l16;
        bf[i] = *(const h8*)&Bs[n * LSTR + kk + quad * 8];
      }
#pragma unroll
      for (int i = 0; i < 4; ++i)
#pragma unroll
        for (int j = 0; j < 4; ++j)
          acc[i][j] = __builtin_amdgcn_mfma_f32_16x16x32_f16(af[i], bf[j], acc[i][j], 0, 0, 0);
    }
  }

  const int cm0 = tm * 128 + wr * 64, cn0 = tn * 128 + wc * 64;
#pragma unroll
  for (int i = 0; i < 4; ++i) {
#pragma unroll
    for (int j = 0; j < 4; ++j) {
      int n = cn0 + j * 16 + l16;
#pragma unroll
      for (int r = 0; r < 4; ++r) {
        int m = cm0 + i * 16 + quad * 4 + r;
        float v = acc[i][j][r];
        if (MODE == 0) {
          v += bias1[n] + bias2[n];
          ((_Float16*)Cout)[(size_t)m * N + n] = (_Float16)v;
        } else {
          if (n < nout) ((float*)Cout)[(size_t)m * nout + n] = v + bias1[n];
        }
      }
    }
  }
}

// ---------------------------------------------------------------------------
// Persistent BiLSTM recurrence, R7.
// Claiming: tid0 reads XCC_ID; xcd<2 -> atomicAdd(cl[xcd]) claims slot (<64).
// Unclaimed blocks bump cl[2] (arrival) and spin until tier-1 full or all
// arrived, then fill deficits via cl[3]; leftovers exit. Block (dir, ib):
// owns units j0=16ib .. +15; wave wv owns units 4wv+rr (rr = lane>>4);
// lane computes 4 GATE dots for its unit over k-slice kq*64..+63.
// hc/hcf: [buf][dir][512] u64, word = [h2 payload | tag32], tag=(epoch<<12)+gen.
// ---------------------------------------------------------------------------
__global__ __launch_bounds__(256, 2) void lstm_rec(
    const float* __restrict__ Whh_f, const float* __restrict__ Whh_b,
    const _Float16* __restrict__ xp,   // [2][2048][4096]
    u64* __restrict__ hc,              // agent-scope mirror [2][2][512]
    u64* __restrict__ hcf,             // fast XCD-L2 buffer [2][2][512]
    unsigned* __restrict__ ep,         // epoch counter (post-incremented)
    int* __restrict__ cl,              // claim counters [8]
    _Float16* __restrict__ hhist) {    // [2048][2048]
  const int tid = threadIdx.x;

  __shared__ int s_dir, s_ib;
  if (tid == 0) {
    int xcd = xcc_id();
    int dir = -1, ib = -1;
    if (xcd < 2) {
      int v = atomicAdd(&cl[xcd], 1);
      if (v < 64) { dir = xcd; ib = v; }
    }
    __hip_atomic_fetch_add(&cl[2], 1, __ATOMIC_ACQ_REL, __HIP_MEMORY_SCOPE_AGENT);
    if (dir < 0) {
      int c0 = 0, c1 = 0, cnt = 0;
      for (;;) {
        c0 = __hip_atomic_load(&cl[0], __ATOMIC_RELAXED, __HIP_MEMORY_SCOPE_AGENT);
        c1 = __hip_atomic_load(&cl[1], __ATOMIC_RELAXED, __HIP_MEMORY_SCOPE_AGENT);
        int arr = __hip_atomic_load(&cl[2], __ATOMIC_ACQUIRE, __HIP_MEMORY_SCOPE_AGENT);
        if ((c0 >= 64 && c1 >= 64) || arr >= (int)gridDim.x || ++cnt > (1 << 20)) break;
      }
      int t0 = c0 < 64 ? c0 : 64, t1 = c1 < 64 ? c1 : 64;
      int d0 = 64 - t0, d1 = 64 - t1;
      if (d0 + d1 > 0) {
        int f = atomicAdd(&cl[3], 1);
        if (f < d0) { dir = 0; ib = t0 + f; }
        else if (f < d0 + d1) { dir = 1; ib = t1 + (f - d0); }
      }
    }
    s_dir = dir; s_ib = ib;
  }
  __syncthreads();
  const int dir = s_dir;
  if (dir < 0) return;
  const int ib = s_ib;

  const int j0 = ib * 16;
  const int wv = tid >> 6;
  const int l = tid & 63;
  const int rr = l >> 4;     // unit replica 0..3 (DPP row)
  const int kq = l & 15;     // 16 k-slices of 64
  const int wrow_u = j0 + 4 * wv + rr;  // unit index within [0,1024)

  const unsigned SB =
      (__hip_atomic_load(ep, __ATOMIC_RELAXED, __HIP_MEMORY_SCOPE_AGENT) - 1u) << 12;

  const float* Whh = dir ? Whh_b : Whh_f;
  const _Float16* xpd = xp + (size_t)dir * (2048u * 4096u);

  __shared__ unsigned int lds_h[2][16 * 36];  // [buf][seg stride 36]

  // one-time: W_hh[g*1024 + wrow_u][kq*64 .. +63] -> f16 regs, g = gate 0..3
  unsigned int w[4][32];
#pragma unroll
  for (int g = 0; g < 4; ++g) {
    const float* wp = Whh + (size_t)(g * 1024 + wrow_u) * 1024 + kq * 64;
#pragma unroll
    for (int i = 0; i < 16; ++i) {
      float4 v = ((const float4*)wp)[i];
      w[g][2 * i] = packh2(v.x, v.y);
      w[g][2 * i + 1] = packh2(v.z, v.w);
    }
  }

  float c = 0.f;  // cell state for unit wrow_u (replicated across 16 lanes)

  // x_proj for t=0: 4 gate preacts of unit wrow_u (stride-1024 scalars)
  float xf0, xf1, xf2, xf3;
  {
    const _Float16* xr = xpd + wrow_u;
    xf0 = (float)xr[0]; xf1 = (float)xr[1024];
    xf2 = (float)xr[2048]; xf3 = (float)xr[3072];
  }

  for (int t = 0; t < T_LEN; ++t) {
    const int buf = t & 1;
    const unsigned exp0 = SB + (unsigned)t;
    // ---- poll own 16B (words 2tid, 2tid+1): L2 fast path, mirror every 4th
    unsigned d0 = 0, d1 = 0;
    {
      const size_t boff = ((size_t)buf * 2 + dir) * 512 + 2 * tid;
      const u64* f = hcf + boff;
      u64* s = hc + boff;
      int cnt = 0;
      for (;;) {
        u32x4 fv;
        load4_sc0(f, fv);  // {tag0, pay0, tag1, pay1}
        if (fv[0] == exp0 && fv[2] == exp0) { d0 = fv[1]; d1 = fv[3]; break; }
        if ((++cnt & 3) == 0) {
          u64 sa = __hip_atomic_load(&s[0], __ATOMIC_RELAXED, __HIP_MEMORY_SCOPE_AGENT);
          u64 sb = __hip_atomic_load(&s[1], __ATOMIC_RELAXED, __HIP_MEMORY_SCOPE_AGENT);
          if ((unsigned)sa == exp0 && (unsigned)sb == exp0) {
            d0 = (unsigned)(sa >> 32);
            d1 = (unsigned)(sb >> 32);
            break;
          }
          if (cnt > (1 << 12)) break;  // bailout: fail absmax, never hang
        }
      }
    }

    // prefetch NEXT step's x_proj (4 gate scalars; off the critical path)
    int tnx = (t + 1 < T_LEN) ? t + 1 : t;
    const _Float16* xr = xpd + (size_t)tnx * 4096 + wrow_u;
    _Float16 n0 = xr[0], n1 = xr[1024], n2 = xr[2048], n3 = xr[3072];

    // stage h payload: dwords 2tid,2tid+1 -> seg tid>>4, offset 2*(tid&15)
    *(uint2*)&lds_h[buf][(tid >> 4) * 36 + 2 * (tid & 15)] = make_uint2(d0, d1);
    __syncthreads();  // single barrier per step

    // ---- dot: 4 gates x 64-elem slice; 8 ds_read_b128, 128 fdot2 ----
    float acc0 = 0.f, acc1 = 0.f, acc2 = 0.f, acc3 = 0.f;
    const uint4* hp = (const uint4*)&lds_h[buf][kq * 36];
#pragma unroll
    for (int i = 0; i < 8; ++i) {
      uint4 hv = hp[i];
      acc0 = fdot2u(w[0][4 * i + 0], hv.x, acc0);
      acc0 = fdot2u(w[0][4 * i + 1], hv.y, acc0);
      acc0 = fdot2u(w[0][4 * i + 2], hv.z, acc0);
      acc0 = fdot2u(w[0][4 * i + 3], hv.w, acc0);
      acc1 = fdot2u(w[1][4 * i + 0], hv.x, acc1);
      acc1 = fdot2u(w[1][4 * i + 1], hv.y, acc1);
      acc1 = fdot2u(w[1][4 * i + 2], hv.z, acc1);
      acc1 = fdot2u(w[1][4 * i + 3], hv.w, acc1);
      acc2 = fdot2u(w[2][4 * i + 0], hv.x, acc2);
      acc2 = fdot2u(w[2][4 * i + 1], hv.y, acc2);
      acc2 = fdot2u(w[2][4 * i + 2], hv.z, acc2);
      acc2 = fdot2u(w[2][4 * i + 3], hv.w, acc2);
      acc3 = fdot2u(w[3][4 * i + 0], hv.x, acc3);
      acc3 = fdot2u(w[3][4 * i + 1], hv.y, acc3);
      acc3 = fdot2u(w[3][4 * i + 2], hv.z, acc3);
      acc3 = fdot2u(w[3][4 * i + 3], hv.w, acc3);
    }
    // 16-lane reduce via DPP (VALU-only): xor1, xor2, 8-mirror, 16-mirror
    DPP_ROUND(0xB1);   // quad_perm {1,0,3,2}
    DPP_ROUND(0x4E);   // quad_perm {2,3,0,1}
    DPP_ROUND(0x141);  // row_half_mirror
    DPP_ROUND(0x140);  // row_mirror

    // lane now holds all 4 gate preacts of unit wrow_u directly
    float ii = sigmoidf_(acc0 + xf0);
    float ff = sigmoidf_(acc1 + xf1);
    float g_ = tanhf_(acc2 + xf2);
    float oo = sigmoidf_(acc3 + xf3);
    c = ff * c + ii * g_;
    float h = oo * tanhf_(c);  // replicated over 16 lanes of row rr

    // publish: pair rows (0,1) and (2,3), then fold rows 2->0; lane0 stores
    float hx = __shfl_xor(h, 16, 64);   // row0 gets h1, row2 gets h3
    unsigned pk = packh2(h, hx);        // row0: (h0,h1)  row2: (h2,h3)
    unsigned pko = (unsigned)__shfl_xor((int)pk, 32, 64);  // row0 gets (h2,h3)
    if (l == 0) {
      unsigned tg = SB + (unsigned)(t + 1);
      size_t widx = ((size_t)((t + 1) & 1) * 2 + dir) * 512 +
                    (size_t)(ib * 8 + 2 * wv);
      // fast publish first (local L2, one 16B store), then mirror, then hist
      *(uint4*)&hcf[widx] = make_uint4(tg, pk, tg, pko);
      u64 w0 = ((u64)pk << 32) | tg;
      u64 w1 = ((u64)pko << 32) | tg;
      __hip_atomic_store(&hc[widx], w0, __ATOMIC_RELAXED, __HIP_MEMORY_SCOPE_AGENT);
      __hip_atomic_store(&hc[widx + 1], w1, __ATOMIC_RELAXED, __HIP_MEMORY_SCOPE_AGENT);
      int tout = dir ? (T_LEN - 1 - t) : t;
      *(uint2*)&hhist[(size_t)tout * 2048 + (size_t)(dir * 1024 + j0 + 4 * wv)] =
          make_uint2(pk, pko);
    }

    // convert next-step xp (prefetched above)
    xf0 = (float)n0; xf1 = (float)n1; xf2 = (float)n2; xf3 = (float)n3;
  }
}

// ---------------------------------------------------------------------------
extern "C" void kernel_launch(void* const* d_in, const int* in_sizes, int n_in,
                              void* d_out, int out_size, void* d_ws, size_t ws_size,
                              hipStream_t stream) {
  (void)in_sizes; (void)n_in; (void)out_size; (void)ws_size;
  const float* x     = (const float*)d_in[0];
  const float* Wih_f = (const float*)d_in[1];
  const float* Whh_f = (const float*)d_in[2];
  const float* bih_f = (const float*)d_in[3];
  const float* bhh_f = (const float*)d_in[4];
  const float* Wih_b = (const float*)d_in[5];
  const float* Whh_b = (const float*)d_in[6];
  const float* bih_b = (const float*)d_in[7];
  const float* bhh_b = (const float*)d_in[8];
  const float* fcW   = (const float*)d_in[9];
  const float* fcb   = (const float*)d_in[10];

  char* ws = (char*)d_ws;
  _Float16* xf16   = (_Float16*)(ws + 0);
  _Float16* wih16f = (_Float16*)(ws + 4194304);
  _Float16* wih16b = (_Float16*)(ws + 12582912);
  _Float16* fcw16  = (_Float16*)(ws + 20971520);
  _Float16* xp16   = (_Float16*)(ws + 25165824);   // [2][2048][4096]
  _Float16* hhist  = (_Float16*)(ws + 58720256);   // [2048][2048]
  u64*      hc     = (u64*)     (ws + 67108864);   // mirror [2][2][512]
  u64*      hcf    = (u64*)     (ws + 67125248);   // fast   [2][2][512]
  unsigned* epoch  = (unsigned*)(ws + 67141632);   // epoch counter
  int*      clm    = (int*)     (ws + 67141696);   // claim counters [8]

  const size_t SX = 2097152, SW = 4194304, SFC = 2097152;
  const size_t total_cvt = SX + 2 * SW + SFC;

  convert_all<<<dim3((unsigned)((total_cvt + 255) / 256)), 256, 0, stream>>>(
      x, Wih_f, Wih_b, fcW, xf16, wih16f, wih16b, fcw16);
  init_state<<<1, 256, 0, stream>>>(hc, hcf, epoch, clm);

  gemm_f16<0><<<dim3(512), 256, 0, stream>>>(xf16, wih16f, bih_f, bhh_f,
                                             (void*)xp16, 2048, 4096, 1024, 4096, 0);
  gemm_f16<0><<<dim3(512), 256, 0, stream>>>(xf16, wih16b, bih_b, bhh_b,
                                             (void*)(xp16 + (size_t)2048 * 4096),
                                             2048, 4096, 1024, 4096, 1);

  lstm_rec<<<dim3(512), 256, 0, stream>>>(Whh_f, Whh_b, xp16, hc, hcf, epoch, clm, hhist);

  gemm_f16<1><<<dim3(128), 256, 0, stream>>>(hhist, fcw16, fcb, nullptr,
                                             d_out, 2048, 1024, 2048, 1000, 0);
}